// Round 1
// baseline (1685.595 us; speedup 1.0000x reference)
//
#include <hip/hip_runtime.h>

// ---------------- problem constants ----------------
constexpr int B_ = 8, T_ = 256, H_ = 64, L_ = 3, NB_ = 17, NF_ = 68, HP_ = 6, K_ = 9, PAD_ = 4;
constexpr int FEAT_DIM = NB_ * H_ + NF_ * H_ + H_;   // 5504

// ---------------- workspace layout (floats) ----------------
constexpr size_t SZ_ABODY = (size_t)B_ * NB_ * H_ * T_;   // 2,228,224
constexpr size_t SZ_AFACE = (size_t)B_ * NF_ * H_ * T_;   // 8,912,896
constexpr size_t OFF_ABODY = 0;
constexpr size_t OFF_AFACE = OFF_ABODY + SZ_ABODY;
constexpr size_t OFF_B     = OFF_AFACE + SZ_AFACE;        // shared tmp (face-sized)
constexpr size_t OFF_C     = OFF_B + SZ_AFACE;            // shared tmp (face-sized)
constexpr size_t OFF_W2    = OFF_C + SZ_AFACE;            // 4 * 3*64*64*9 = 442,368
constexpr size_t OFF_B2    = OFF_W2 + 4 * 110592;         // 4 * 192 = 768
constexpr size_t OFF_ADJTB = OFF_B2 + 768;                // 289 -> pad 320
constexpr size_t OFF_ADJTF = OFF_ADJTB + 320;             // 4624 -> pad 4640
constexpr size_t OFF_FEAT  = OFF_ADJTF + 4640;            // 8*5504
constexpr size_t OFF_P1    = OFF_FEAT + (size_t)B_ * FEAT_DIM;
constexpr size_t WS_TOTAL  = OFF_P1 + (size_t)B_ * 256;   // ~117.9 MB

// ---------------- prep: fold BN into conv weights, transpose to [l][i][k][o] ----------------
__global__ void prep_conv(const float* __restrict__ w, const float* __restrict__ tb,
                          const float* __restrict__ g, const float* __restrict__ bb,
                          const float* __restrict__ m, const float* __restrict__ v,
                          float* __restrict__ w2, float* __restrict__ b2) {
    int idx = blockIdx.x * 256 + threadIdx.x;
    const int per_l = H_ * H_ * K_;   // 36864
    if (idx >= L_ * per_l) return;
    int l = idx / per_l, r = idx % per_l;
    int o = r / (H_ * K_), r2 = r % (H_ * K_);
    int i = r2 / K_, k = r2 % K_;
    float sc = g[l * H_ + o] / sqrtf(v[l * H_ + o] + 1e-5f);
    w2[(size_t)l * per_l + (i * K_ + k) * H_ + o] = w[idx] * sc;
    if (r2 == 0)
        b2[l * H_ + o] = tb[l * H_ + o] * sc + bb[l * H_ + o] - m[l * H_ + o] * sc;
}

__global__ void prep_adj(const float* __restrict__ adj, float* __restrict__ adjT, int N) {
    int idx = blockIdx.x * 256 + threadIdx.x;
    if (idx >= N * N) return;
    int n = idx / N, mm = idx % N;
    adjT[idx] = adj[mm * N + n];   // adjT[n][m]
}

// ---------------- projection: (B,T,N,2) @ (2,H) + b -> (B,N,H,T) ----------------
template <int N>
__global__ __launch_bounds__(256) void proj_kernel(const float* __restrict__ kps,
                                                   const float* __restrict__ pw,
                                                   const float* __restrict__ pb,
                                                   float* __restrict__ out) {
    int bn = blockIdx.x;
    int b = bn / N, n = bn % N;
    int t = threadIdx.x;
    float x0 = kps[((size_t)b * T_ + t) * (N * 2) + n * 2 + 0];
    float x1 = kps[((size_t)b * T_ + t) * (N * 2) + n * 2 + 1];
    float* ob = out + (size_t)bn * H_ * T_ + t;
#pragma unroll 8
    for (int c = 0; c < H_; ++c)
        ob[(size_t)c * T_] = fmaf(x0, pw[c], fmaf(x1, pw[H_ + c], pb[c]));
}

// ---------------- conv1d(K=9,pad=4) + folded BN (+relu / +residual) ----------------
// block = (bn, t-chunk of 64); wave w owns output channels [16w,16w+16)
template <bool RELU, bool RESID>
__global__ __launch_bounds__(256) void conv_bn_kernel(const float* __restrict__ x,
                                                      const float* __restrict__ w2,
                                                      const float* __restrict__ b2,
                                                      const float* __restrict__ res,
                                                      float* __restrict__ out, int l) {
    __shared__ float Xs[H_ * 72];
    int bn = blockIdx.x >> 2;
    int tc = blockIdx.x & 3;
    int tid = threadIdx.x;
    const float* xb = x + (size_t)bn * H_ * T_;
    for (int idx = tid; idx < H_ * 72; idx += 256) {
        int i = idx / 72, tt = idx % 72;
        int t = tc * 64 - PAD_ + tt;
        Xs[idx] = (t >= 0 && t < T_) ? xb[(size_t)i * T_ + t] : 0.0f;
    }
    __syncthreads();
    int tl = tid & 63;
    int obase = __builtin_amdgcn_readfirstlane(tid >> 6) * 16;
    const float* wbase = w2 + (size_t)l * (H_ * H_ * K_) + obase;
    float acc[16];
#pragma unroll
    for (int oo = 0; oo < 16; ++oo) acc[oo] = 0.f;
    for (int i = 0; i < H_; ++i) {
#pragma unroll
        for (int k = 0; k < K_; ++k) {
            float xv = Xs[i * 72 + tl + k];
            const float* wr = wbase + (i * K_ + k) * H_;
#pragma unroll
            for (int oo = 0; oo < 16; ++oo)
                acc[oo] = fmaf(wr[oo], xv, acc[oo]);
        }
    }
    int t = tc * 64 + tl;
    const float* bb = b2 + l * H_ + obase;
#pragma unroll
    for (int oo = 0; oo < 16; ++oo) {
        float y = acc[oo] + bb[oo];
        if (RELU) y = fmaxf(y, 0.f);
        size_t oidx = ((size_t)bn * H_ + obase + oo) * T_ + t;
        if (RESID) y += res[oidx];
        out[oidx] = y;
    }
}

// ---------------- GCN channel mix: out[b,n,o,t] = sum_c x[b,n,c,t] * gw[l][c][o] ----------------
__global__ __launch_bounds__(256) void support_kernel(const float* __restrict__ x,
                                                      const float* __restrict__ gw,
                                                      float* __restrict__ out, int l) {
    __shared__ float Xs[H_ * 64];
    int bn = blockIdx.x >> 2;
    int tc = blockIdx.x & 3;
    int tid = threadIdx.x;
    const float* xb = x + (size_t)bn * H_ * T_ + tc * 64;
    for (int idx = tid; idx < H_ * 64; idx += 256) {
        int c = idx >> 6, t = idx & 63;
        Xs[idx] = xb[(size_t)c * T_ + t];
    }
    __syncthreads();
    int tl = tid & 63;
    int obase = __builtin_amdgcn_readfirstlane(tid >> 6) * 16;
    const float* gwl = gw + (size_t)l * H_ * H_ + obase;
    float acc[16];
#pragma unroll
    for (int oo = 0; oo < 16; ++oo) acc[oo] = 0.f;
    for (int c = 0; c < H_; ++c) {
        float xv = Xs[(c << 6) + tl];
        const float* wr = gwl + c * H_;
#pragma unroll
        for (int oo = 0; oo < 16; ++oo)
            acc[oo] = fmaf(wr[oo], xv, acc[oo]);
    }
    float* ob = out + (size_t)bn * H_ * T_ + tc * 64 + tl;
#pragma unroll
    for (int oo = 0; oo < 16; ++oo)
        ob[(size_t)(obase + oo) * T_] = acc[oo];
}

// ---------------- adj mix: out[b,m,o,t] = relu( sum_n adj[m,n]*sup[b,n,o,t] + gb[o] ) ----------------
template <int N>
__global__ __launch_bounds__(256) void adjmix_kernel(const float* __restrict__ sup,
                                                     const float* __restrict__ adjT,
                                                     const float* __restrict__ gb,
                                                     float* __restrict__ out, int l) {
    constexpr int TC = 128;
    constexpr int MT = N / 17;   // 1 (body) or 4 (face)
    __shared__ float Ls[N * TC];
    int blk = blockIdx.x;
    int tc = blk & 1;
    int o = (blk >> 1) & 63;
    int b = blk >> 7;
    int tid = threadIdx.x;
    const float* supb = sup + ((size_t)b * N * H_ + o) * T_ + tc * TC;
    for (int idx = tid; idx < N * TC; idx += 256) {
        int n = idx >> 7, t = idx & 127;
        Ls[idx] = supb[(size_t)n * H_ * T_ + t];
    }
    __syncthreads();
    int t = tid & 127;
    int gq = tid >> 7;   // 0..1 splits m-tiles
    float gbv = gb[l * H_ + o];
    for (int mt = gq; mt < MT; mt += 2) {
        float acc[17];
#pragma unroll
        for (int mm = 0; mm < 17; ++mm) acc[mm] = 0.f;
        for (int n = 0; n < N; ++n) {
            float xv = Ls[(n << 7) + t];
            const float* ar = adjT + n * N + mt * 17;
#pragma unroll
            for (int mm = 0; mm < 17; ++mm)
                acc[mm] = fmaf(ar[mm], xv, acc[mm]);
        }
#pragma unroll
        for (int mm = 0; mm < 17; ++mm) {
            int m = mt * 17 + mm;
            out[((size_t)(b * N + m) * H_ + o) * T_ + tc * TC + t] = fmaxf(acc[mm] + gbv, 0.f);
        }
    }
}

// ---------------- temporal mean pool -> feat ----------------
template <int N>
__global__ __launch_bounds__(256) void meanpool_kernel(const float* __restrict__ x,
                                                       float* __restrict__ feat, int base) {
    __shared__ float red[256];
    int bn = blockIdx.x;
    int b = bn / N, n = bn % N;
    int tid = threadIdx.x;
    int c = tid >> 2, q = tid & 3;
    const float* xb = x + ((size_t)bn * H_ + c) * T_;
    float acc = 0.f;
#pragma unroll 8
    for (int j = 0; j < 64; ++j) acc += xb[q + 4 * j];
    red[tid] = acc;
    __syncthreads();
    if (q == 0) {
        float s = red[tid] + red[tid + 1] + red[tid + 2] + red[tid + 3];
        feat[(size_t)b * FEAT_DIM + base + n * H_ + c] = s * (1.f / 256.f);
    }
}

// ---------------- head stream ----------------
__global__ void head_kernel(const float* __restrict__ x, const float* __restrict__ hw,
                            const float* __restrict__ hb, float* __restrict__ feat) {
    int b = blockIdx.x;
    int c = threadIdx.x;   // 64
    float w0 = hw[c], w1 = hw[64 + c], w2 = hw[128 + c],
          w3 = hw[192 + c], w4 = hw[256 + c], w5 = hw[320 + c];
    float bias = hb[c];
    float acc = 0.f;
    for (int t = 0; t < T_; ++t) {
        const float* xr = x + ((size_t)b * T_ + t) * HP_;
        float s = fmaf(xr[0], w0, fmaf(xr[1], w1, fmaf(xr[2], w2,
                  fmaf(xr[3], w3, fmaf(xr[4], w4, fmaf(xr[5], w5, bias))))));
        acc += fmaxf(s, 0.f);
    }
    feat[(size_t)b * FEAT_DIM + NB_ * H_ + NF_ * H_ + c] = acc * (1.f / 256.f);
}

// ---------------- fusion layer 1 (5504 -> 256), split over i with atomics ----------------
__global__ __launch_bounds__(256) void fus1_kernel(const float* __restrict__ feat,
                                                   const float* __restrict__ w1,
                                                   float* __restrict__ p1) {
    int b = blockIdx.x >> 2, ic = blockIdx.x & 3;
    int o = threadIdx.x;
    const float* fb = feat + (size_t)b * FEAT_DIM + ic * 1376;
    const float* wb = w1 + (size_t)ic * 1376 * 256 + o;
    float acc = 0.f;
    for (int i = 0; i < 1376; ++i)
        acc = fmaf(fb[i], wb[(size_t)i * 256], acc);
    atomicAdd(&p1[b * 256 + o], acc);
}

// ---------------- fusion tail: relu -> 256->128->64->5 ----------------
__global__ __launch_bounds__(256) void fus_tail_kernel(const float* __restrict__ p1,
        const float* __restrict__ b1, const float* __restrict__ w2, const float* __restrict__ b2,
        const float* __restrict__ w3, const float* __restrict__ b3,
        const float* __restrict__ w4, const float* __restrict__ b4, float* __restrict__ out) {
    __shared__ float s1[256], s2[128], s3[64];
    int b = blockIdx.x, tid = threadIdx.x;
    s1[tid] = fmaxf(p1[b * 256 + tid] + b1[tid], 0.f);
    __syncthreads();
    if (tid < 128) {
        float acc = b2[tid];
        for (int i = 0; i < 256; ++i) acc = fmaf(s1[i], w2[i * 128 + tid], acc);
        s2[tid] = fmaxf(acc, 0.f);
    }
    __syncthreads();
    if (tid < 64) {
        float acc = b3[tid];
        for (int i = 0; i < 128; ++i) acc = fmaf(s2[i], w3[i * 64 + tid], acc);
        s3[tid] = fmaxf(acc, 0.f);
    }
    __syncthreads();
    if (tid < 5) {
        float acc = b4[tid];
        for (int i = 0; i < 64; ++i) acc = fmaf(s3[i], w4[i * 5 + tid], acc);
        out[b * 5 + tid] = acc;
    }
}

// ---------------- launch ----------------
extern "C" void kernel_launch(void* const* d_in, const int* in_sizes, int n_in,
                              void* d_out, int out_size, void* d_ws, size_t ws_size,
                              hipStream_t stream) {
    const float* body_kps = (const float*)d_in[0];
    const float* face_kps = (const float*)d_in[1];
    const float* head_pose = (const float*)d_in[2];
    const float* body_adj = (const float*)d_in[3];
    const float* face_adj = (const float*)d_in[4];
    const float* body_pw = (const float*)d_in[5];
    const float* body_pb = (const float*)d_in[6];
    const float* face_pw = (const float*)d_in[7];
    const float* face_pb = (const float*)d_in[8];
    const float* head_w = (const float*)d_in[9];
    const float* head_b = (const float*)d_in[10];
    // per-stream params: b at 11, f at 25
    const float* b_t1w = (const float*)d_in[11]; const float* b_t1b = (const float*)d_in[12];
    const float* b_g1  = (const float*)d_in[13]; const float* b_b1  = (const float*)d_in[14];
    const float* b_m1  = (const float*)d_in[15]; const float* b_v1  = (const float*)d_in[16];
    const float* b_gcw = (const float*)d_in[17]; const float* b_gcb = (const float*)d_in[18];
    const float* b_t2w = (const float*)d_in[19]; const float* b_t2b = (const float*)d_in[20];
    const float* b_g2  = (const float*)d_in[21]; const float* b_b2  = (const float*)d_in[22];
    const float* b_m2  = (const float*)d_in[23]; const float* b_v2  = (const float*)d_in[24];
    const float* f_t1w = (const float*)d_in[25]; const float* f_t1b = (const float*)d_in[26];
    const float* f_g1  = (const float*)d_in[27]; const float* f_b1  = (const float*)d_in[28];
    const float* f_m1  = (const float*)d_in[29]; const float* f_v1  = (const float*)d_in[30];
    const float* f_gcw = (const float*)d_in[31]; const float* f_gcb = (const float*)d_in[32];
    const float* f_t2w = (const float*)d_in[33]; const float* f_t2b = (const float*)d_in[34];
    const float* f_g2  = (const float*)d_in[35]; const float* f_b2  = (const float*)d_in[36];
    const float* f_m2  = (const float*)d_in[37]; const float* f_v2  = (const float*)d_in[38];
    const float* fus1_w = (const float*)d_in[39]; const float* fus1_b = (const float*)d_in[40];
    const float* fus2_w = (const float*)d_in[41]; const float* fus2_b = (const float*)d_in[42];
    const float* fus3_w = (const float*)d_in[43]; const float* fus3_b = (const float*)d_in[44];
    const float* fus4_w = (const float*)d_in[45]; const float* fus4_b = (const float*)d_in[46];

    float* ws = (float*)d_ws;
    float* A_body = ws + OFF_ABODY;
    float* A_face = ws + OFF_AFACE;
    float* Bsh = ws + OFF_B;
    float* Csh = ws + OFF_C;
    float* W2b1 = ws + OFF_W2;            float* B2b1 = ws + OFF_B2;
    float* W2b2 = ws + OFF_W2 + 110592;   float* B2b2 = ws + OFF_B2 + 192;
    float* W2f1 = ws + OFF_W2 + 221184;   float* B2f1 = ws + OFF_B2 + 384;
    float* W2f2 = ws + OFF_W2 + 331776;   float* B2f2 = ws + OFF_B2 + 576;
    float* adjT_b = ws + OFF_ADJTB;
    float* adjT_f = ws + OFF_ADJTF;
    float* feat = ws + OFF_FEAT;
    float* p1 = ws + OFF_P1;
    float* out = (float*)d_out;

    // prep
    int pg = (L_ * H_ * H_ * K_ + 255) / 256;   // 432
    prep_conv<<<pg, 256, 0, stream>>>(b_t1w, b_t1b, b_g1, b_b1, b_m1, b_v1, W2b1, B2b1);
    prep_conv<<<pg, 256, 0, stream>>>(b_t2w, b_t2b, b_g2, b_b2, b_m2, b_v2, W2b2, B2b2);
    prep_conv<<<pg, 256, 0, stream>>>(f_t1w, f_t1b, f_g1, f_b1, f_m1, f_v1, W2f1, B2f1);
    prep_conv<<<pg, 256, 0, stream>>>(f_t2w, f_t2b, f_g2, f_b2, f_m2, f_v2, W2f2, B2f2);
    prep_adj<<<2, 256, 0, stream>>>(body_adj, adjT_b, NB_);
    prep_adj<<<19, 256, 0, stream>>>(face_adj, adjT_f, NF_);
    hipMemsetAsync(p1, 0, (size_t)B_ * 256 * sizeof(float), stream);

    // projections
    proj_kernel<NB_><<<B_ * NB_, 256, 0, stream>>>(body_kps, body_pw, body_pb, A_body);
    proj_kernel<NF_><<<B_ * NF_, 256, 0, stream>>>(face_kps, face_pw, face_pb, A_face);

    const int gb_conv = B_ * NB_ * 4;   // 544
    const int gf_conv = B_ * NF_ * 4;   // 2176
    const int g_adj = B_ * H_ * 2;      // 1024

    for (int l = 0; l < L_; ++l) {
        // body
        conv_bn_kernel<true, false><<<gb_conv, 256, 0, stream>>>(A_body, W2b1, B2b1, nullptr, Bsh, l);
        support_kernel<<<gb_conv, 256, 0, stream>>>(Bsh, b_gcw, Csh, l);
        adjmix_kernel<NB_><<<g_adj, 256, 0, stream>>>(Csh, adjT_b, b_gcb, Bsh, l);
        conv_bn_kernel<false, true><<<gb_conv, 256, 0, stream>>>(Bsh, W2b2, B2b2, A_body, A_body, l);
        // face
        conv_bn_kernel<true, false><<<gf_conv, 256, 0, stream>>>(A_face, W2f1, B2f1, nullptr, Bsh, l);
        support_kernel<<<gf_conv, 256, 0, stream>>>(Bsh, f_gcw, Csh, l);
        adjmix_kernel<NF_><<<g_adj, 256, 0, stream>>>(Csh, adjT_f, f_gcb, Bsh, l);
        conv_bn_kernel<false, true><<<gf_conv, 256, 0, stream>>>(Bsh, W2f2, B2f2, A_face, A_face, l);
    }

    // pooling + head + fusion
    meanpool_kernel<NB_><<<B_ * NB_, 256, 0, stream>>>(A_body, feat, 0);
    meanpool_kernel<NF_><<<B_ * NF_, 256, 0, stream>>>(A_face, feat, NB_ * H_);
    head_kernel<<<B_, 64, 0, stream>>>(head_pose, head_w, head_b, feat);
    fus1_kernel<<<B_ * 4, 256, 0, stream>>>(feat, fus1_w, p1);
    fus_tail_kernel<<<B_, 256, 0, stream>>>(p1, fus1_b, fus2_w, fus2_b, fus3_w, fus3_b,
                                            fus4_w, fus4_b, out);
}

// Round 2
// 913.536 us; speedup vs baseline: 1.8451x; 1.8451x over previous
//
#include <hip/hip_runtime.h>

// ---------------- problem constants ----------------
constexpr int B_ = 8, T_ = 256, H_ = 64, L_ = 3, NB_ = 17, NF_ = 68, HP_ = 6, K_ = 9, PAD_ = 4;
constexpr int FEAT_DIM = NB_ * H_ + NF_ * H_ + H_;   // 5504

typedef _Float16 half4_t __attribute__((ext_vector_type(4)));
typedef _Float16 half8_t __attribute__((ext_vector_type(8)));
typedef float f32x16 __attribute__((ext_vector_type(16)));

// ---------------- workspace layout (floats) ----------------
constexpr size_t SZ_ABODY = (size_t)B_ * NB_ * H_ * T_;   // 2,228,224
constexpr size_t SZ_AFACE = (size_t)B_ * NF_ * H_ * T_;   // 8,912,896
constexpr size_t OFF_ABODY = 0;
constexpr size_t OFF_AFACE = OFF_ABODY + SZ_ABODY;
constexpr size_t OFF_B     = OFF_AFACE + SZ_AFACE;
constexpr size_t OFF_C     = OFF_B + SZ_AFACE;
constexpr size_t OFF_W3    = OFF_C + SZ_AFACE;            // 4 conv sets x 55296 floats (f16 x2)
constexpr size_t OFF_GW3   = OFF_W3 + 4 * 55296;          // 2 gcw sets x 6144 floats
constexpr size_t OFF_B2    = OFF_GW3 + 2 * 6144;          // 4 x 192
constexpr size_t OFF_ADJTB = OFF_B2 + 768;
constexpr size_t OFF_ADJTF = OFF_ADJTB + 320;
constexpr size_t OFF_FEAT  = OFF_ADJTF + 4640;
constexpr size_t OFF_P1    = OFF_FEAT + (size_t)B_ * FEAT_DIM;

// ---------------- prep: fold BN into conv W, f16, layout [l][k][i8][o][j] ----------------
__global__ void prep_convW(const float* __restrict__ w, const float* __restrict__ tb,
                           const float* __restrict__ g, const float* __restrict__ bb,
                           const float* __restrict__ m, const float* __restrict__ v,
                           _Float16* __restrict__ w3, float* __restrict__ b2) {
    int idx = blockIdx.x * 256 + threadIdx.x;
    if (idx >= L_ * H_ * H_ * K_) return;
    int k = idx % K_; int r = idx / K_;
    int i = r % H_; r /= H_;
    int o = r % H_; int l = r / H_;
    float sc = g[l * H_ + o] * rsqrtf(v[l * H_ + o] + 1e-5f);
    w3[((((l * K_ + k) * 8 + (i >> 3)) * H_ + o) * 8) + (i & 7)] = (_Float16)(w[idx] * sc);
    if (i == 0 && k == 0)
        b2[l * H_ + o] = tb[l * H_ + o] * sc + bb[l * H_ + o] - m[l * H_ + o] * sc;
}

// gcw (L,H:c,H:o) -> f16 [l][c8][o][j]
__global__ void prep_gcw(const float* __restrict__ gw, _Float16* __restrict__ w3) {
    int idx = blockIdx.x * 256 + threadIdx.x;
    if (idx >= L_ * H_ * H_) return;
    int o = idx % H_; int r = idx / H_;
    int c = r % H_; int l = r / H_;
    w3[(((l * 8 + (c >> 3)) * H_ + o) * 8) + (c & 7)] = (_Float16)gw[idx];
}

__global__ void prep_adj(const float* __restrict__ adj, float* __restrict__ adjT, int N) {
    int idx = blockIdx.x * 256 + threadIdx.x;
    if (idx >= N * N) return;
    int n = idx / N, mm = idx % N;
    adjT[idx] = adj[mm * N + n];   // adjT[n][m]
}

// ---------------- projection: (B,T,N,2) @ (2,H) + b -> (B,N,H,T) ----------------
template <int N>
__global__ __launch_bounds__(256) void proj_kernel(const float* __restrict__ kps,
                                                   const float* __restrict__ pw,
                                                   const float* __restrict__ pb,
                                                   float* __restrict__ out) {
    int bn = blockIdx.x;
    int b = bn / N, n = bn % N;
    int t = threadIdx.x;
    float x0 = kps[((size_t)b * T_ + t) * (N * 2) + n * 2 + 0];
    float x1 = kps[((size_t)b * T_ + t) * (N * 2) + n * 2 + 1];
    float* ob = out + (size_t)bn * H_ * T_ + t;
#pragma unroll 8
    for (int c = 0; c < H_; ++c)
        ob[(size_t)c * T_] = fmaf(x0, pw[c], fmaf(x1, pw[H_ + c], pb[c]));
}

// ---------------- MFMA f16 GEMM: out[o][t] = sum_{i,tap} W[o][i][tap] * x[i][t+tap-PAD] ----------------
// block = (bn, t-chunk of 128); 4 waves, wave w covers t in [tc*128 + w*32, +32), all 64 o.
// NT = taps (9 = conv, 1 = channel-mix GEMM).
template <int NT, bool RELU, bool RESID, bool HASB>
__global__ __launch_bounds__(256) void gemm_f16(const float* __restrict__ x,
                                                const half8_t* __restrict__ w3,
                                                const float* __restrict__ b2,
                                                const float* __restrict__ res,
                                                float* __restrict__ out, int l) {
    constexpr int TCH = 128;
    constexpr int ROWS = TCH + NT - 1;
    constexpr int PADn = (NT - 1) / 2;
    __shared__ __align__(16) _Float16 Xs[ROWS * 68];
    int blk = blockIdx.x;
    int bn = blk >> 1, tc = blk & 1;
    int tid = threadIdx.x;
    const float* xb = x + (size_t)bn * H_ * T_;
    for (int idx = tid; idx < H_ * ROWS; idx += 256) {
        int c = idx / ROWS, tt = idx % ROWS;
        int t = tc * TCH + tt - PADn;
        float vv = (t >= 0 && t < T_) ? xb[c * T_ + t] : 0.f;
        Xs[tt * 68 + c] = (_Float16)vv;
    }
    __syncthreads();

    int ln = tid & 63;
    int w = __builtin_amdgcn_readfirstlane(tid >> 6);
    int ln31 = ln & 31, kg = ln >> 5;

    f32x16 acc[2];
#pragma unroll
    for (int mt = 0; mt < 2; ++mt)
#pragma unroll
        for (int r = 0; r < 16; ++r) acc[mt][r] = 0.f;

    const half8_t* wl = w3 + (size_t)l * NT * 8 * H_;   // half8 units per layer
    const _Float16* xrow0 = Xs + (size_t)(w * 32 + ln31) * 68;

#pragma unroll
    for (int tap = 0; tap < NT; ++tap) {
#pragma unroll
        for (int ks = 0; ks < 4; ++ks) {
            int i8 = ks * 2 + kg;
            half8_t a0 = wl[(tap * 8 + i8) * H_ + ln31];
            half8_t a1 = wl[(tap * 8 + i8) * H_ + 32 + ln31];
            const _Float16* p = xrow0 + tap * 68 + i8 * 8;
            half4_t blo = *(const half4_t*)p;
            half4_t bhi = *(const half4_t*)(p + 4);
            half8_t bb8 = __builtin_shufflevector(blo, bhi, 0, 1, 2, 3, 4, 5, 6, 7);
            acc[0] = __builtin_amdgcn_mfma_f32_32x32x16_f16(a0, bb8, acc[0], 0, 0, 0);
            acc[1] = __builtin_amdgcn_mfma_f32_32x32x16_f16(a1, bb8, acc[1], 0, 0, 0);
        }
    }

    int t = tc * TCH + w * 32 + ln31;
#pragma unroll
    for (int mt = 0; mt < 2; ++mt) {
#pragma unroll
        for (int r = 0; r < 16; ++r) {
            int o = mt * 32 + (r & 3) + 8 * (r >> 2) + 4 * kg;
            float y = acc[mt][r];
            if (HASB) y += b2[l * H_ + o];
            if (RELU) y = fmaxf(y, 0.f);
            size_t oi = ((size_t)bn * H_ + o) * T_ + t;
            if (RESID) y += res[oi];
            out[oi] = y;
        }
    }
}

// ---------------- adj mix: out[b,m,o,t] = relu( sum_n adj[m,n]*sup[b,n,o,t] + gb[o] ) ----------------
template <int N>
__global__ __launch_bounds__(256) void adjmix_kernel(const float* __restrict__ sup,
                                                     const float* __restrict__ adjT,
                                                     const float* __restrict__ gb,
                                                     float* __restrict__ out, int l) {
    constexpr int TC = 128;
    constexpr int MT = N / 17;   // 1 (body) or 4 (face)
    __shared__ float Ls[N * TC];
    int blk = blockIdx.x;
    int tc = blk & 1;
    int o = (blk >> 1) & 63;
    int b = blk >> 7;
    int tid = threadIdx.x;
    const float* supb = sup + ((size_t)b * N * H_ + o) * T_ + tc * TC;
    for (int idx = tid; idx < N * TC; idx += 256) {
        int n = idx >> 7, t = idx & 127;
        Ls[idx] = supb[(size_t)n * H_ * T_ + t];
    }
    __syncthreads();
    int t = tid & 127;
    int gq = tid >> 7;
    float gbv = gb[l * H_ + o];
    for (int mt = gq; mt < MT; mt += 2) {
        float acc[17];
#pragma unroll
        for (int mm = 0; mm < 17; ++mm) acc[mm] = 0.f;
        for (int n = 0; n < N; ++n) {
            float xv = Ls[(n << 7) + t];
            const float* ar = adjT + n * N + mt * 17;
#pragma unroll
            for (int mm = 0; mm < 17; ++mm)
                acc[mm] = fmaf(ar[mm], xv, acc[mm]);
        }
#pragma unroll
        for (int mm = 0; mm < 17; ++mm) {
            int m = mt * 17 + mm;
            out[((size_t)(b * N + m) * H_ + o) * T_ + tc * TC + t] = fmaxf(acc[mm] + gbv, 0.f);
        }
    }
}

// ---------------- temporal mean pool -> feat ----------------
template <int N>
__global__ __launch_bounds__(256) void meanpool_kernel(const float* __restrict__ x,
                                                       float* __restrict__ feat, int base) {
    __shared__ float red[256];
    int bn = blockIdx.x;
    int b = bn / N, n = bn % N;
    int tid = threadIdx.x;
    int c = tid >> 2, q = tid & 3;
    const float* xb = x + ((size_t)bn * H_ + c) * T_;
    float acc = 0.f;
#pragma unroll 8
    for (int j = 0; j < 64; ++j) acc += xb[q + 4 * j];
    red[tid] = acc;
    __syncthreads();
    if (q == 0) {
        float s = red[tid] + red[tid + 1] + red[tid + 2] + red[tid + 3];
        feat[(size_t)b * FEAT_DIM + base + n * H_ + c] = s * (1.f / 256.f);
    }
}

// ---------------- head stream ----------------
__global__ void head_kernel(const float* __restrict__ x, const float* __restrict__ hw,
                            const float* __restrict__ hb, float* __restrict__ feat) {
    int b = blockIdx.x;
    int c = threadIdx.x;   // 64
    float w0 = hw[c], w1 = hw[64 + c], w2 = hw[128 + c],
          w3 = hw[192 + c], w4 = hw[256 + c], w5 = hw[320 + c];
    float bias = hb[c];
    float acc = 0.f;
    for (int t = 0; t < T_; ++t) {
        const float* xr = x + ((size_t)b * T_ + t) * HP_;
        float s = fmaf(xr[0], w0, fmaf(xr[1], w1, fmaf(xr[2], w2,
                  fmaf(xr[3], w3, fmaf(xr[4], w4, fmaf(xr[5], w5, bias))))));
        acc += fmaxf(s, 0.f);
    }
    feat[(size_t)b * FEAT_DIM + NB_ * H_ + NF_ * H_ + c] = acc * (1.f / 256.f);
}

// ---------------- fusion layer 1 (5504 -> 256) ----------------
__global__ __launch_bounds__(256) void fus1_kernel(const float* __restrict__ feat,
                                                   const float* __restrict__ w1,
                                                   float* __restrict__ p1) {
    int b = blockIdx.x >> 2, ic = blockIdx.x & 3;
    int o = threadIdx.x;
    const float* fb = feat + (size_t)b * FEAT_DIM + ic * 1376;
    const float* wb = w1 + (size_t)ic * 1376 * 256 + o;
    float acc = 0.f;
    for (int i = 0; i < 1376; ++i)
        acc = fmaf(fb[i], wb[(size_t)i * 256], acc);
    atomicAdd(&p1[b * 256 + o], acc);
}

// ---------------- fusion tail ----------------
__global__ __launch_bounds__(256) void fus_tail_kernel(const float* __restrict__ p1,
        const float* __restrict__ b1, const float* __restrict__ w2, const float* __restrict__ b2,
        const float* __restrict__ w3, const float* __restrict__ b3,
        const float* __restrict__ w4, const float* __restrict__ b4, float* __restrict__ out) {
    __shared__ float s1[256], s2[128], s3[64];
    int b = blockIdx.x, tid = threadIdx.x;
    s1[tid] = fmaxf(p1[b * 256 + tid] + b1[tid], 0.f);
    __syncthreads();
    if (tid < 128) {
        float acc = b2[tid];
        for (int i = 0; i < 256; ++i) acc = fmaf(s1[i], w2[i * 128 + tid], acc);
        s2[tid] = fmaxf(acc, 0.f);
    }
    __syncthreads();
    if (tid < 64) {
        float acc = b3[tid];
        for (int i = 0; i < 128; ++i) acc = fmaf(s2[i], w3[i * 64 + tid], acc);
        s3[tid] = fmaxf(acc, 0.f);
    }
    __syncthreads();
    if (tid < 5) {
        float acc = b4[tid];
        for (int i = 0; i < 64; ++i) acc = fmaf(s3[i], w4[i * 5 + tid], acc);
        out[b * 5 + tid] = acc;
    }
}

// ---------------- launch ----------------
extern "C" void kernel_launch(void* const* d_in, const int* in_sizes, int n_in,
                              void* d_out, int out_size, void* d_ws, size_t ws_size,
                              hipStream_t stream) {
    const float* body_kps = (const float*)d_in[0];
    const float* face_kps = (const float*)d_in[1];
    const float* head_pose = (const float*)d_in[2];
    const float* body_adj = (const float*)d_in[3];
    const float* face_adj = (const float*)d_in[4];
    const float* body_pw = (const float*)d_in[5];
    const float* body_pb = (const float*)d_in[6];
    const float* face_pw = (const float*)d_in[7];
    const float* face_pb = (const float*)d_in[8];
    const float* head_w = (const float*)d_in[9];
    const float* head_b = (const float*)d_in[10];
    const float* b_t1w = (const float*)d_in[11]; const float* b_t1b = (const float*)d_in[12];
    const float* b_g1  = (const float*)d_in[13]; const float* b_b1  = (const float*)d_in[14];
    const float* b_m1  = (const float*)d_in[15]; const float* b_v1  = (const float*)d_in[16];
    const float* b_gcw = (const float*)d_in[17]; const float* b_gcb = (const float*)d_in[18];
    const float* b_t2w = (const float*)d_in[19]; const float* b_t2b = (const float*)d_in[20];
    const float* b_g2  = (const float*)d_in[21]; const float* b_b2  = (const float*)d_in[22];
    const float* b_m2  = (const float*)d_in[23]; const float* b_v2  = (const float*)d_in[24];
    const float* f_t1w = (const float*)d_in[25]; const float* f_t1b = (const float*)d_in[26];
    const float* f_g1  = (const float*)d_in[27]; const float* f_b1  = (const float*)d_in[28];
    const float* f_m1  = (const float*)d_in[29]; const float* f_v1  = (const float*)d_in[30];
    const float* f_gcw = (const float*)d_in[31]; const float* f_gcb = (const float*)d_in[32];
    const float* f_t2w = (const float*)d_in[33]; const float* f_t2b = (const float*)d_in[34];
    const float* f_g2  = (const float*)d_in[35]; const float* f_b2  = (const float*)d_in[36];
    const float* f_m2  = (const float*)d_in[37]; const float* f_v2  = (const float*)d_in[38];
    const float* fus1_w = (const float*)d_in[39]; const float* fus1_b = (const float*)d_in[40];
    const float* fus2_w = (const float*)d_in[41]; const float* fus2_b = (const float*)d_in[42];
    const float* fus3_w = (const float*)d_in[43]; const float* fus3_b = (const float*)d_in[44];
    const float* fus4_w = (const float*)d_in[45]; const float* fus4_b = (const float*)d_in[46];

    float* ws = (float*)d_ws;
    float* A_body = ws + OFF_ABODY;
    float* A_face = ws + OFF_AFACE;
    float* Bsh = ws + OFF_B;
    float* Csh = ws + OFF_C;
    _Float16* W3b1 = (_Float16*)(ws + OFF_W3);
    _Float16* W3b2 = (_Float16*)(ws + OFF_W3 + 55296);
    _Float16* W3f1 = (_Float16*)(ws + OFF_W3 + 2 * 55296);
    _Float16* W3f2 = (_Float16*)(ws + OFF_W3 + 3 * 55296);
    _Float16* GW3b = (_Float16*)(ws + OFF_GW3);
    _Float16* GW3f = (_Float16*)(ws + OFF_GW3 + 6144);
    float* B2b1 = ws + OFF_B2;        float* B2b2 = ws + OFF_B2 + 192;
    float* B2f1 = ws + OFF_B2 + 384;  float* B2f2 = ws + OFF_B2 + 576;
    float* adjT_b = ws + OFF_ADJTB;
    float* adjT_f = ws + OFF_ADJTF;
    float* feat = ws + OFF_FEAT;
    float* p1 = ws + OFF_P1;
    float* out = (float*)d_out;

    // prep
    int pg = (L_ * H_ * H_ * K_ + 255) / 256;   // 432
    prep_convW<<<pg, 256, 0, stream>>>(b_t1w, b_t1b, b_g1, b_b1, b_m1, b_v1, W3b1, B2b1);
    prep_convW<<<pg, 256, 0, stream>>>(b_t2w, b_t2b, b_g2, b_b2, b_m2, b_v2, W3b2, B2b2);
    prep_convW<<<pg, 256, 0, stream>>>(f_t1w, f_t1b, f_g1, f_b1, f_m1, f_v1, W3f1, B2f1);
    prep_convW<<<pg, 256, 0, stream>>>(f_t2w, f_t2b, f_g2, f_b2, f_m2, f_v2, W3f2, B2f2);
    prep_gcw<<<48, 256, 0, stream>>>(b_gcw, GW3b);
    prep_gcw<<<48, 256, 0, stream>>>(f_gcw, GW3f);
    prep_adj<<<2, 256, 0, stream>>>(body_adj, adjT_b, NB_);
    prep_adj<<<19, 256, 0, stream>>>(face_adj, adjT_f, NF_);
    hipMemsetAsync(p1, 0, (size_t)B_ * 256 * sizeof(float), stream);

    // projections
    proj_kernel<NB_><<<B_ * NB_, 256, 0, stream>>>(body_kps, body_pw, body_pb, A_body);
    proj_kernel<NF_><<<B_ * NF_, 256, 0, stream>>>(face_kps, face_pw, face_pb, A_face);

    const int gb = B_ * NB_ * 2;    // 272
    const int gf = B_ * NF_ * 2;    // 1088
    const int g_adj = B_ * H_ * 2;  // 1024

    for (int l = 0; l < L_; ++l) {
        // body
        gemm_f16<9, true, false, true><<<gb, 256, 0, stream>>>(A_body, (const half8_t*)W3b1, B2b1, nullptr, Bsh, l);
        gemm_f16<1, false, false, false><<<gb, 256, 0, stream>>>(Bsh, (const half8_t*)GW3b, nullptr, nullptr, Csh, l);
        adjmix_kernel<NB_><<<g_adj, 256, 0, stream>>>(Csh, adjT_b, b_gcb, Bsh, l);
        gemm_f16<9, false, true, true><<<gb, 256, 0, stream>>>(Bsh, (const half8_t*)W3b2, B2b2, A_body, A_body, l);
        // face
        gemm_f16<9, true, false, true><<<gf, 256, 0, stream>>>(A_face, (const half8_t*)W3f1, B2f1, nullptr, Bsh, l);
        gemm_f16<1, false, false, false><<<gf, 256, 0, stream>>>(Bsh, (const half8_t*)GW3f, nullptr, nullptr, Csh, l);
        adjmix_kernel<NF_><<<g_adj, 256, 0, stream>>>(Csh, adjT_f, f_gcb, Bsh, l);
        gemm_f16<9, false, true, true><<<gf, 256, 0, stream>>>(Bsh, (const half8_t*)W3f2, B2f2, A_face, A_face, l);
    }

    // pooling + head + fusion
    meanpool_kernel<NB_><<<B_ * NB_, 256, 0, stream>>>(A_body, feat, 0);
    meanpool_kernel<NF_><<<B_ * NF_, 256, 0, stream>>>(A_face, feat, NB_ * H_);
    head_kernel<<<B_, 64, 0, stream>>>(head_pose, head_w, head_b, feat);
    fus1_kernel<<<B_ * 4, 256, 0, stream>>>(feat, fus1_w, p1);
    fus_tail_kernel<<<B_, 256, 0, stream>>>(p1, fus1_b, fus2_w, fus2_b, fus3_w, fus3_b,
                                            fus4_w, fus4_b, out);
}

// Round 3
// 517.747 us; speedup vs baseline: 3.2556x; 1.7644x over previous
//
#include <hip/hip_runtime.h>

// ---------------- problem constants ----------------
constexpr int B_ = 8, T_ = 256, H_ = 64, L_ = 3, NB_ = 17, NF_ = 68, HP_ = 6, K_ = 9;
constexpr int FEAT_DIM = NB_ * H_ + NF_ * H_ + H_;   // 5504
constexpr int HT = H_ * T_;                          // 16384

typedef _Float16 half4_t __attribute__((ext_vector_type(4)));
typedef _Float16 half8_t __attribute__((ext_vector_type(8)));
typedef float f32x16 __attribute__((ext_vector_type(16)));
typedef float f32x4 __attribute__((ext_vector_type(4)));

// ---------------- workspace layout (float units) ----------------
constexpr size_t SZ_AB = (size_t)B_ * NB_ * HT;   // 2,228,224
constexpr size_t SZ_AF = (size_t)B_ * NF_ * HT;   // 8,912,896
constexpr size_t OFF_AB   = 0;
constexpr size_t OFF_AF   = OFF_AB + SZ_AB;
constexpr size_t OFF_B16B = OFF_AF + SZ_AF;           // f16 buffers (half the float count)
constexpr size_t OFF_B16F = OFF_B16B + SZ_AB / 2;
constexpr size_t OFF_C16B = OFF_B16F + SZ_AF / 2;
constexpr size_t OFF_C16F = OFF_C16B + SZ_AB / 2;
constexpr size_t OFF_W3   = OFF_C16F + SZ_AF / 2;     // 4 conv sets x 110592 f16
constexpr size_t OFF_GW3  = OFF_W3 + 4 * 55296;       // 2 x 12288 f16
constexpr size_t OFF_B2   = OFF_GW3 + 2 * 6144;       // 4 x 192 f32
constexpr size_t OFF_ADJPB= OFF_B2 + 768;             // 32x32 f16
constexpr size_t OFF_ADJPF= OFF_ADJPB + 512;          // 96x80 f16
constexpr size_t OFF_FEAT = OFF_ADJPF + 3840;
constexpr size_t OFF_P1   = OFF_FEAT + (size_t)B_ * FEAT_DIM;

// ---------------- prep: fold BN into conv W -> f16 [l][k][i8][o][j], 4 sets ----------------
struct ConvPrepSet { const float *w, *tb, *g, *bb, *m, *v; };

__global__ __launch_bounds__(256) void prep_convW_all(ConvPrepSet s0, ConvPrepSet s1,
                                                      ConvPrepSet s2, ConvPrepSet s3,
                                                      _Float16* __restrict__ w3,
                                                      float* __restrict__ b2) {
    int set = blockIdx.y;
    ConvPrepSet s = (set == 0) ? s0 : (set == 1) ? s1 : (set == 2) ? s2 : s3;
    int idx = blockIdx.x * 256 + threadIdx.x;           // < 110592
    int k = idx % K_; int r = idx / K_;
    int i = r % H_; r /= H_;
    int o = r % H_; int l = r / H_;
    float sc = s.g[l * H_ + o] * rsqrtf(s.v[l * H_ + o] + 1e-5f);
    w3[(size_t)set * 110592 + ((((l * K_ + k) * 8 + (i >> 3)) * H_ + o) * 8) + (i & 7)]
        = (_Float16)(s.w[idx] * sc);
    if (i == 0 && k == 0)
        b2[set * 192 + l * H_ + o] =
            s.tb[l * H_ + o] * sc + s.bb[l * H_ + o] - s.m[l * H_ + o] * sc;
}

// gcw (L,c,o) -> f16 [l][c8][o][j], 2 sets
__global__ __launch_bounds__(256) void prep_gcw_all(const float* __restrict__ g0,
                                                    const float* __restrict__ g1,
                                                    _Float16* __restrict__ w3) {
    int set = blockIdx.y;
    const float* gw = set ? g1 : g0;
    int idx = blockIdx.x * 256 + threadIdx.x;           // < 12288
    int o = idx % H_; int r = idx / H_;
    int c = r % H_; int l = r / H_;
    w3[(size_t)set * 12288 + (((l * 8 + (c >> 3)) * H_ + o) * 8) + (c & 7)] = (_Float16)gw[idx];
}

// padded f16 adj (A-operand layout, row-major m x Kpad) + zero p1
__global__ __launch_bounds__(256) void prep_misc(const float* __restrict__ adjB,
                                                 const float* __restrict__ adjF,
                                                 _Float16* __restrict__ pB,
                                                 _Float16* __restrict__ pF,
                                                 float* __restrict__ p1) {
    int idx = blockIdx.x * 256 + threadIdx.x;
    if (idx < 32 * 32) {
        int m = idx >> 5, k = idx & 31;
        pB[idx] = (m < NB_ && k < NB_) ? (_Float16)adjB[m * NB_ + k] : (_Float16)0.f;
    } else if (idx < 1024 + 96 * 80) {
        int j = idx - 1024;
        int m = j / 80, k = j % 80;
        pF[j] = (m < NF_ && k < NF_) ? (_Float16)adjF[m * NF_ + k] : (_Float16)0.f;
    } else if (idx < 1024 + 7680 + B_ * 256) {
        p1[idx - 8704] = 0.f;
    }
}

// ---------------- projection: (B,T,N,2) @ (2,H) + b -> (B,N,H,T) f32 ----------------
template <int N>
__global__ __launch_bounds__(256) void proj_kernel(const float* __restrict__ kps,
                                                   const float* __restrict__ pw,
                                                   const float* __restrict__ pb,
                                                   float* __restrict__ out) {
    int bn = blockIdx.x;
    int b = bn / N, n = bn % N;
    int t = threadIdx.x;
    float x0 = kps[((size_t)b * T_ + t) * (N * 2) + n * 2 + 0];
    float x1 = kps[((size_t)b * T_ + t) * (N * 2) + n * 2 + 1];
    float* ob = out + (size_t)bn * HT + t;
#pragma unroll 8
    for (int c = 0; c < H_; ++c)
        ob[(size_t)c * T_] = fmaf(x0, pw[c], fmaf(x1, pw[H_ + c], pb[c]));
}

// ---------------- MFMA f16 GEMM (conv NT=9 / channel-mix NT=1), body+face merged ----------------
template <int NT, bool IN16, bool OUT16, bool RELU, bool RESID, bool HASB>
__global__ __launch_bounds__(256) void gemm_f16(
        const void* __restrict__ x0, const half8_t* __restrict__ w30,
        const float* __restrict__ b20, const float* __restrict__ res0, void* __restrict__ out0,
        const void* __restrict__ x1, const half8_t* __restrict__ w31,
        const float* __restrict__ b21, const float* __restrict__ res1, void* __restrict__ out1,
        int nblk0, int l) {
    constexpr int ROWS = 128 + NT - 1;      // 136 or 128
    constexpr int SEGS = ROWS / 8;          // 17 or 16
    constexpr int PADn = (NT - 1) / 2;
    __shared__ __align__(16) _Float16 Xs[ROWS * 68];

    int blk = blockIdx.x;
    const void* xp; const half8_t* w3; const float* b2v; const float* res; void* outp;
    if (blk < nblk0) { xp = x0; w3 = w30; b2v = b20; res = res0; outp = out0; }
    else { blk -= nblk0; xp = x1; w3 = w31; b2v = b21; res = res1; outp = out1; }
    int bn = blk >> 1, tc = blk & 1;
    int tid = threadIdx.x;

    for (int u = tid; u < H_ * SEGS; u += 256) {
        int c = u / SEGS, s = u % SEGS;
        int t0 = tc * 128 + s * 8 - PADn;
        _Float16 v[8];
        if (IN16) {
            const _Float16* xr = (const _Float16*)xp + (size_t)bn * HT + c * T_;
            if (t0 >= 0 && t0 + 8 <= T_) {
                half4_t a = *(const half4_t*)(xr + t0);
                half4_t bq = *(const half4_t*)(xr + t0 + 4);
#pragma unroll
                for (int j = 0; j < 4; ++j) { v[j] = a[j]; v[4 + j] = bq[j]; }
            } else {
#pragma unroll
                for (int j = 0; j < 8; ++j) {
                    int t = t0 + j;
                    v[j] = (t >= 0 && t < T_) ? xr[t] : (_Float16)0.f;
                }
            }
        } else {
            const float* xr = (const float*)xp + (size_t)bn * HT + c * T_;
            if (t0 >= 0 && t0 + 8 <= T_) {
                f32x4 a = *(const f32x4*)(xr + t0);
                f32x4 bq = *(const f32x4*)(xr + t0 + 4);
#pragma unroll
                for (int j = 0; j < 4; ++j) { v[j] = (_Float16)a[j]; v[4 + j] = (_Float16)bq[j]; }
            } else {
#pragma unroll
                for (int j = 0; j < 8; ++j) {
                    int t = t0 + j;
                    v[j] = (t >= 0 && t < T_) ? (_Float16)xr[t] : (_Float16)0.f;
                }
            }
        }
        int tt = s * 8;
#pragma unroll
        for (int j = 0; j < 8; ++j) Xs[(tt + j) * 68 + c] = v[j];
    }
    __syncthreads();

    int ln = tid & 63;
    int w = __builtin_amdgcn_readfirstlane(tid >> 6);
    int ln31 = ln & 31, kg = ln >> 5;

    f32x16 acc[2];
#pragma unroll
    for (int mt = 0; mt < 2; ++mt)
#pragma unroll
        for (int r = 0; r < 16; ++r) acc[mt][r] = 0.f;

    const half8_t* wl = w3 + (size_t)l * NT * 8 * H_;
    const _Float16* xrow0 = Xs + (size_t)(w * 32 + ln31) * 68;

#pragma unroll
    for (int tap = 0; tap < NT; ++tap) {
#pragma unroll
        for (int ks = 0; ks < 4; ++ks) {
            int i8 = ks * 2 + kg;
            half8_t a0 = wl[(tap * 8 + i8) * H_ + ln31];
            half8_t a1 = wl[(tap * 8 + i8) * H_ + 32 + ln31];
            const _Float16* p = xrow0 + tap * 68 + i8 * 8;
            half4_t blo = *(const half4_t*)p;
            half4_t bhi = *(const half4_t*)(p + 4);
            half8_t bb8 = __builtin_shufflevector(blo, bhi, 0, 1, 2, 3, 4, 5, 6, 7);
            acc[0] = __builtin_amdgcn_mfma_f32_32x32x16_f16(a0, bb8, acc[0], 0, 0, 0);
            acc[1] = __builtin_amdgcn_mfma_f32_32x32x16_f16(a1, bb8, acc[1], 0, 0, 0);
        }
    }

    int t = tc * 128 + w * 32 + ln31;
#pragma unroll
    for (int mt = 0; mt < 2; ++mt) {
#pragma unroll
        for (int r = 0; r < 16; ++r) {
            int o = mt * 32 + (r & 3) + 8 * (r >> 2) + 4 * kg;
            float y = acc[mt][r];
            if (HASB) y += b2v[l * H_ + o];
            if (RELU) y = fmaxf(y, 0.f);
            size_t oi = (size_t)bn * HT + (size_t)o * T_ + t;
            if (OUT16) {
                ((_Float16*)outp)[oi] = (_Float16)y;
            } else {
                if (RESID) y += res[oi];
                ((float*)outp)[oi] = y;
            }
        }
    }
}

// ---------------- adjmix as MFMA: out[b,m,col] = relu(sum_n adj[m,n] sup[b,n,col] + gb) ----------------
template <int N, int MT, int KS>   // MT m-tiles of 32, KS k-slices of 16
__device__ __forceinline__ void adjmix_impl(const _Float16* __restrict__ sup,
                                            const _Float16* __restrict__ adjP,
                                            const float* __restrict__ gb,
                                            _Float16* __restrict__ out,
                                            int blk, int l, _Float16* Ls, int tid) {
    constexpr int KP = KS * 16;
    constexpr int PITCH = 136;
    int b = blk >> 7, cb = blk & 127;
    int colbase = cb * 128;
    float gbv = gb[l * H_ + (cb >> 1)];   // o = colbase/T, 128 cols never straddle o

    for (int u = tid; u < KP * 16; u += 256) {
        int n = u >> 4, cs = u & 15;
        half8_t v = {(_Float16)0.f, (_Float16)0.f, (_Float16)0.f, (_Float16)0.f,
                     (_Float16)0.f, (_Float16)0.f, (_Float16)0.f, (_Float16)0.f};
        if (n < N) v = *(const half8_t*)(sup + (size_t)(b * N + n) * HT + colbase + cs * 8);
        *(half8_t*)(Ls + n * PITCH + cs * 8) = v;
    }
    __syncthreads();

    int ln = tid & 63;
    int w = __builtin_amdgcn_readfirstlane(tid >> 6);
    int ln31 = ln & 31, kg = ln >> 5;

    f32x16 acc[MT];
#pragma unroll
    for (int mt = 0; mt < MT; ++mt)
#pragma unroll
        for (int r = 0; r < 16; ++r) acc[mt][r] = 0.f;

#pragma unroll
    for (int ks = 0; ks < KS; ++ks) {
        half8_t bf;
        const _Float16* bp = Ls + (ks * 16 + kg * 8) * PITCH + w * 32 + ln31;
#pragma unroll
        for (int j = 0; j < 8; ++j) bf[j] = bp[j * PITCH];
#pragma unroll
        for (int mt = 0; mt < MT; ++mt) {
            half8_t af = *(const half8_t*)(adjP + (size_t)(mt * 32 + ln31) * KP + ks * 16 + kg * 8);
            acc[mt] = __builtin_amdgcn_mfma_f32_32x32x16_f16(af, bf, acc[mt], 0, 0, 0);
        }
    }

    int col = colbase + w * 32 + ln31;
#pragma unroll
    for (int mt = 0; mt < MT; ++mt) {
#pragma unroll
        for (int r = 0; r < 16; ++r) {
            int m = mt * 32 + (r & 3) + 8 * (r >> 2) + 4 * kg;
            if (m < N)
                out[(size_t)(b * N + m) * HT + col] = (_Float16)fmaxf(acc[mt][r] + gbv, 0.f);
        }
    }
}

__global__ __launch_bounds__(256) void adjmix_kernel(
        const _Float16* __restrict__ supB, const _Float16* __restrict__ adjPB,
        const float* __restrict__ gbB, _Float16* __restrict__ outB,
        const _Float16* __restrict__ supF, const _Float16* __restrict__ adjPF,
        const float* __restrict__ gbF, _Float16* __restrict__ outF,
        int nblk0, int l) {
    __shared__ __align__(16) _Float16 Ls[80 * 136];
    int blk = blockIdx.x, tid = threadIdx.x;
    if (blk < nblk0)
        adjmix_impl<NB_, 1, 2>(supB, adjPB, gbB, outB, blk, l, Ls, tid);
    else
        adjmix_impl<NF_, 3, 5>(supF, adjPF, gbF, outF, blk - nblk0, l, Ls, tid);
}

// ---------------- temporal mean pool -> feat ----------------
template <int N>
__global__ __launch_bounds__(256) void meanpool_kernel(const float* __restrict__ x,
                                                       float* __restrict__ feat, int base) {
    __shared__ float red[256];
    int bn = blockIdx.x;
    int b = bn / N, n = bn % N;
    int tid = threadIdx.x;
    int c = tid >> 2, q = tid & 3;
    const float* xb = x + ((size_t)bn * H_ + c) * T_;
    float acc = 0.f;
#pragma unroll 8
    for (int j = 0; j < 64; ++j) acc += xb[q + 4 * j];
    red[tid] = acc;
    __syncthreads();
    if (q == 0) {
        float s = red[tid] + red[tid + 1] + red[tid + 2] + red[tid + 3];
        feat[(size_t)b * FEAT_DIM + base + n * H_ + c] = s * (1.f / 256.f);
    }
}

// ---------------- head stream ----------------
__global__ void head_kernel(const float* __restrict__ x, const float* __restrict__ hw,
                            const float* __restrict__ hb, float* __restrict__ feat) {
    int b = blockIdx.x;
    int c = threadIdx.x;   // 64
    float w0 = hw[c], w1 = hw[64 + c], w2 = hw[128 + c],
          w3 = hw[192 + c], w4 = hw[256 + c], w5 = hw[320 + c];
    float bias = hb[c];
    float acc = 0.f;
    for (int t = 0; t < T_; ++t) {
        const float* xr = x + ((size_t)b * T_ + t) * HP_;
        float s = fmaf(xr[0], w0, fmaf(xr[1], w1, fmaf(xr[2], w2,
                  fmaf(xr[3], w3, fmaf(xr[4], w4, fmaf(xr[5], w5, bias))))));
        acc += fmaxf(s, 0.f);
    }
    feat[(size_t)b * FEAT_DIM + NB_ * H_ + NF_ * H_ + c] = acc * (1.f / 256.f);
}

// ---------------- fusion layer 1 (5504 -> 256) ----------------
__global__ __launch_bounds__(256) void fus1_kernel(const float* __restrict__ feat,
                                                   const float* __restrict__ w1,
                                                   float* __restrict__ p1) {
    int b = blockIdx.x >> 2, ic = blockIdx.x & 3;
    int o = threadIdx.x;
    const float* fb = feat + (size_t)b * FEAT_DIM + ic * 1376;
    const float* wb = w1 + (size_t)ic * 1376 * 256 + o;
    float acc = 0.f;
    for (int i = 0; i < 1376; ++i)
        acc = fmaf(fb[i], wb[(size_t)i * 256], acc);
    atomicAdd(&p1[b * 256 + o], acc);
}

// ---------------- fusion tail ----------------
__global__ __launch_bounds__(256) void fus_tail_kernel(const float* __restrict__ p1,
        const float* __restrict__ b1, const float* __restrict__ w2, const float* __restrict__ b2,
        const float* __restrict__ w3, const float* __restrict__ b3,
        const float* __restrict__ w4, const float* __restrict__ b4, float* __restrict__ out) {
    __shared__ float s1[256], s2[128], s3[64];
    int b = blockIdx.x, tid = threadIdx.x;
    s1[tid] = fmaxf(p1[b * 256 + tid] + b1[tid], 0.f);
    __syncthreads();
    if (tid < 128) {
        float acc = b2[tid];
        for (int i = 0; i < 256; ++i) acc = fmaf(s1[i], w2[i * 128 + tid], acc);
        s2[tid] = fmaxf(acc, 0.f);
    }
    __syncthreads();
    if (tid < 64) {
        float acc = b3[tid];
        for (int i = 0; i < 128; ++i) acc = fmaf(s2[i], w3[i * 64 + tid], acc);
        s3[tid] = fmaxf(acc, 0.f);
    }
    __syncthreads();
    if (tid < 5) {
        float acc = b4[tid];
        for (int i = 0; i < 64; ++i) acc = fmaf(s3[i], w4[i * 5 + tid], acc);
        out[b * 5 + tid] = acc;
    }
}

// ---------------- launch ----------------
extern "C" void kernel_launch(void* const* d_in, const int* in_sizes, int n_in,
                              void* d_out, int out_size, void* d_ws, size_t ws_size,
                              hipStream_t stream) {
    const float* body_kps = (const float*)d_in[0];
    const float* face_kps = (const float*)d_in[1];
    const float* head_pose = (const float*)d_in[2];
    const float* body_adj = (const float*)d_in[3];
    const float* face_adj = (const float*)d_in[4];
    const float* body_pw = (const float*)d_in[5];
    const float* body_pb = (const float*)d_in[6];
    const float* face_pw = (const float*)d_in[7];
    const float* face_pb = (const float*)d_in[8];
    const float* head_w = (const float*)d_in[9];
    const float* head_b = (const float*)d_in[10];
    const float* b_t1w = (const float*)d_in[11]; const float* b_t1b = (const float*)d_in[12];
    const float* b_g1  = (const float*)d_in[13]; const float* b_b1  = (const float*)d_in[14];
    const float* b_m1  = (const float*)d_in[15]; const float* b_v1  = (const float*)d_in[16];
    const float* b_gcw = (const float*)d_in[17]; const float* b_gcb = (const float*)d_in[18];
    const float* b_t2w = (const float*)d_in[19]; const float* b_t2b = (const float*)d_in[20];
    const float* b_g2  = (const float*)d_in[21]; const float* b_b2  = (const float*)d_in[22];
    const float* b_m2  = (const float*)d_in[23]; const float* b_v2  = (const float*)d_in[24];
    const float* f_t1w = (const float*)d_in[25]; const float* f_t1b = (const float*)d_in[26];
    const float* f_g1  = (const float*)d_in[27]; const float* f_b1  = (const float*)d_in[28];
    const float* f_m1  = (const float*)d_in[29]; const float* f_v1  = (const float*)d_in[30];
    const float* f_gcw = (const float*)d_in[31]; const float* f_gcb = (const float*)d_in[32];
    const float* f_t2w = (const float*)d_in[33]; const float* f_t2b = (const float*)d_in[34];
    const float* f_g2  = (const float*)d_in[35]; const float* f_b2  = (const float*)d_in[36];
    const float* f_m2  = (const float*)d_in[37]; const float* f_v2  = (const float*)d_in[38];
    const float* fus1_w = (const float*)d_in[39]; const float* fus1_b = (const float*)d_in[40];
    const float* fus2_w = (const float*)d_in[41]; const float* fus2_b = (const float*)d_in[42];
    const float* fus3_w = (const float*)d_in[43]; const float* fus3_b = (const float*)d_in[44];
    const float* fus4_w = (const float*)d_in[45]; const float* fus4_b = (const float*)d_in[46];

    float* ws = (float*)d_ws;
    float* A_body = ws + OFF_AB;
    float* A_face = ws + OFF_AF;
    _Float16* B16b = (_Float16*)(ws + OFF_B16B);
    _Float16* B16f = (_Float16*)(ws + OFF_B16F);
    _Float16* C16b = (_Float16*)(ws + OFF_C16B);
    _Float16* C16f = (_Float16*)(ws + OFF_C16F);
    _Float16* W3 = (_Float16*)(ws + OFF_W3);
    _Float16* W3b1 = W3;            _Float16* W3b2 = W3 + 110592;
    _Float16* W3f1 = W3 + 221184;   _Float16* W3f2 = W3 + 331776;
    _Float16* GW3 = (_Float16*)(ws + OFF_GW3);
    _Float16* GW3b = GW3;           _Float16* GW3f = GW3 + 12288;
    float* B2 = ws + OFF_B2;
    float* B2b1 = B2;        float* B2b2 = B2 + 192;
    float* B2f1 = B2 + 384;  float* B2f2 = B2 + 576;
    _Float16* adjPB = (_Float16*)(ws + OFF_ADJPB);
    _Float16* adjPF = (_Float16*)(ws + OFF_ADJPF);
    float* feat = ws + OFF_FEAT;
    float* p1 = ws + OFF_P1;
    float* out = (float*)d_out;

    // prep (3 dispatches)
    ConvPrepSet sb1{b_t1w, b_t1b, b_g1, b_b1, b_m1, b_v1};
    ConvPrepSet sb2{b_t2w, b_t2b, b_g2, b_b2, b_m2, b_v2};
    ConvPrepSet sf1{f_t1w, f_t1b, f_g1, f_b1, f_m1, f_v1};
    ConvPrepSet sf2{f_t2w, f_t2b, f_g2, f_b2, f_m2, f_v2};
    prep_convW_all<<<dim3(432, 4), 256, 0, stream>>>(sb1, sb2, sf1, sf2, W3, B2);
    prep_gcw_all<<<dim3(48, 2), 256, 0, stream>>>(b_gcw, f_gcw, GW3);
    prep_misc<<<42, 256, 0, stream>>>(body_adj, face_adj, adjPB, adjPF, p1);

    // projections
    proj_kernel<NB_><<<B_ * NB_, 256, 0, stream>>>(body_kps, body_pw, body_pb, A_body);
    proj_kernel<NF_><<<B_ * NF_, 256, 0, stream>>>(face_kps, face_pw, face_pb, A_face);

    const int gb = B_ * NB_ * 2;    // 272
    const int gf = B_ * NF_ * 2;    // 1088
    const int ga = B_ * 128;        // 1024 per stream

    for (int l = 0; l < L_; ++l) {
        // conv1 + bn + relu : f32 trunk -> f16
        gemm_f16<9, false, true, true, false, true><<<gb + gf, 256, 0, stream>>>(
            A_body, (const half8_t*)W3b1, B2b1, nullptr, B16b,
            A_face, (const half8_t*)W3f1, B2f1, nullptr, B16f, gb, l);
        // channel mix : f16 -> f16
        gemm_f16<1, true, true, false, false, false><<<gb + gf, 256, 0, stream>>>(
            B16b, (const half8_t*)GW3b, nullptr, nullptr, C16b,
            B16f, (const half8_t*)GW3f, nullptr, nullptr, C16f, gb, l);
        // node mix + bias + relu : f16 -> f16 (reuses B16 buffers)
        adjmix_kernel<<<2 * ga, 256, 0, stream>>>(C16b, adjPB, b_gcb, B16b,
                                                  C16f, adjPF, f_gcb, B16f, ga, l);
        // conv2 + bn + residual : f16 -> f32 trunk
        gemm_f16<9, true, false, false, true, true><<<gb + gf, 256, 0, stream>>>(
            B16b, (const half8_t*)W3b2, B2b2, A_body, A_body,
            B16f, (const half8_t*)W3f2, B2f2, A_face, A_face, gb, l);
    }

    // pooling + head + fusion
    meanpool_kernel<NB_><<<B_ * NB_, 256, 0, stream>>>(A_body, feat, 0);
    meanpool_kernel<NF_><<<B_ * NF_, 256, 0, stream>>>(A_face, feat, NB_ * H_);
    head_kernel<<<B_, 64, 0, stream>>>(head_pose, head_w, head_b, feat);
    fus1_kernel<<<B_ * 4, 256, 0, stream>>>(feat, fus1_w, p1);
    fus_tail_kernel<<<B_, 256, 0, stream>>>(p1, fus1_b, fus2_w, fus2_b, fus3_w, fus3_b,
                                            fus4_w, fus4_b, out);
}